// Round 3
// baseline (730.340 us; speedup 1.0000x reference)
//
#include <hip/hip_runtime.h>
#include <math.h>

#define DIM 192
#define HEADS 6
#define HD 32
#define WS 7
#define NN 49
#define NWIN 4096
#define QKV_ROW (3*DIM)

typedef __attribute__((ext_vector_type(8))) short bf16x8_t;
typedef __attribute__((ext_vector_type(4))) float f32x4_t;

#define MFMA16(a,b,c) __builtin_amdgcn_mfma_f32_16x16x32_bf16((a),(b),(c),0,0,0)

__device__ __forceinline__ float gelu_tanh(float x) {
    const float k0 = 0.7978845608028654f; // sqrt(2/pi)
    const float k1 = 0.044715f;
    float t = tanhf(k0 * (x + k1 * x * x * x));
    return 0.5f * x * (1.0f + t);
}

// native bf16 casts -> compiler emits packed v_cvt_pk_bf16_f32 (RNE)
__device__ __forceinline__ unsigned short f2bf(float f) {
    __bf16 h = (__bf16)f;
    return __builtin_bit_cast(unsigned short, h);
}
__device__ __forceinline__ float bf2f(unsigned short u) {
    return (float)__builtin_bit_cast(__bf16, u);
}

// ws layout: bias_frag (6*64*64 f32 = 98304 B) | wbf (192*192 bf16 = 73728 B)
#define BIASF_FLOATS (HEADS*64*64)
#define WBF_OFF_B    (BIASF_FLOATS*4)

// ---------------- bias kernel: frag layout [h][row64][lrow16][4] ----------------
__global__ __launch_bounds__(128) void bias_kernel(
    const float* __restrict__ pos_w, const float* __restrict__ pos_scale,
    const float* __restrict__ meta_w1, const float* __restrict__ meta_b1,
    const float* __restrict__ meta_w2, const float* __restrict__ meta_b2,
    float* __restrict__ bias_frag)
{
    const int p = blockIdx.x;          // n*49+m
    const int n = p / NN, m = p % NN;
    const int i = threadIdx.x;         // 0..127
    __shared__ float hbuf[128];
    const float step = 2.0f / 6.0f;
    const float dx = (float)((n % WS) - (m % WS)) * step;
    const float dy = (float)((n / WS) - (m / WS)) * step;
    const float ps = pos_scale[0];
    float a = meta_b1[i];
    for (int d = 0; d < DIM; ++d) {
        float rel = ps * (pos_w[2*d] * dx + pos_w[2*d+1] * dy); // pos_b cancels
        a += rel * meta_w1[d*128 + i];
    }
    hbuf[i] = gelu_tanh(a);
    __syncthreads();
    if (i < HEADS) {
        float b = meta_b2[i];
        for (int j = 0; j < 128; ++j) b += hbuf[j] * meta_w2[j*HEADS + i];
        bias_frag[((i*64 + n)*16 + (m & 15))*4 + (m >> 4)] = b;
    }
}

// ---------------- prep: W -> bf16, zero bias_frag pad rows ----------------
__global__ __launch_bounds__(256) void prep_w(
    const float* __restrict__ proj_w, unsigned short* __restrict__ wbf,
    float* __restrict__ bias_frag)
{
    int idx = blockIdx.x*256 + threadIdx.x;
    if (idx < DIM*DIM) wbf[idx] = f2bf(proj_w[idx]);
    int z = idx - DIM*DIM;
    if (z >= 0 && z < HEADS*15*64) {
        int hh = z / 960, rem = z - hh*960;
        int row = 49 + (rem >> 6), inner = rem & 63;
        bias_frag[(hh*64 + row)*64 + inner] = 0.f;
    }
}

// gate scratch layout (floats, per half; half stride 320 for 16B alignment)
#define CM 0
#define HB 32
#define CA 40
#define SM 72
#define SX 121
#define SB 170
#define SW 219   // sa_w copy, 98 floats
#define GSZ 320

// LDS row strides (bf16 elems)
#define RSQ 40   // q_s/k_s: 80B
#define RSV 72   // v_t/p_s: 144B

__global__ __launch_bounds__(256, 5) void win_attn_mfma(
    const float* __restrict__ qkv,
    const float* __restrict__ log_temp,
    const float* __restrict__ q_ca_w1, const float* __restrict__ q_ca_b1,
    const float* __restrict__ q_ca_w2, const float* __restrict__ q_ca_b2,
    const float* __restrict__ q_sa_w, const float* __restrict__ q_sa_b,
    const float* __restrict__ k_ca_w1, const float* __restrict__ k_ca_b1,
    const float* __restrict__ k_ca_w2, const float* __restrict__ k_ca_b2,
    const float* __restrict__ k_sa_w, const float* __restrict__ k_sa_b,
    const float* __restrict__ bias_frag,
    const unsigned short* __restrict__ wbf,
    float* __restrict__ out)
{
    __shared__ unsigned short q_s[64*RSQ];   // gated Q, later O
    __shared__ unsigned short k_s[64*RSQ];   // gated K
    __shared__ unsigned short v_t[32*RSV];   // V^T [d][m]
    __shared__ unsigned short p_s[64*RSV];   // P [n][m]
    __shared__ float gsc[2*GSZ];

    const int t = threadIdx.x;
    const int b = blockIdx.x;
    const int l = t & 63;
    const int w = t >> 6;          // wave / row-strip
    const int lrow = l & 15;
    const int lk = l >> 4;
    const float temp = __expf(log_temp[0]);
    const float* qkv_b = qkv + (size_t)b * (NN*QKV_ROW);

    // gate partition: threads 0-127 -> q; 128-255 -> k
    const int kh = t >> 7;
    const int tt = t & 127;
    const int wv = tt >> 6;        // gate-wave within half
    const int ln = tt & 63;
    unsigned short* xs = kh ? k_s : q_s;
    const float* ca_w1 = kh ? k_ca_w1 : q_ca_w1;
    const float* ca_b1 = kh ? k_ca_b1 : q_ca_b1;
    const float* ca_w2 = kh ? k_ca_w2 : q_ca_w2;
    const float* ca_b2 = kh ? k_ca_b2 : q_ca_b2;
    const float* sa_w  = kh ? k_sa_w  : q_sa_w;
    const float* sa_b  = kh ? k_sa_b  : q_sa_b;
    float* sc = gsc + kh*GSZ;
    const float sab = sa_b[0];

    f32x4_t pacc[12];
    #pragma unroll
    for (int j = 0; j < 12; ++j) pacc[j] = (f32x4_t){0.f,0.f,0.f,0.f};

    // one-time: zero pads, cache sa_w in LDS
    for (int i = t; i < 15*RSQ; i += 256) { q_s[49*RSQ + i] = 0; k_s[49*RSQ + i] = 0; }
    for (int i = t; i < 32*23; i += 256) { int d = i/23, m = 49 + (i - d*23); v_t[d*RSV + m] = 0; }
    if (tt < 2*NN) sc[SW + tt] = sa_w[tt];

    #pragma unroll 1
    for (int h = 0; h < HEADS; ++h) {
        // ---- stage q,k,v head slice (fp32 -> bf16) ----
        for (int e = t; e < NN*8; e += 256) {
            int n = e >> 3, c = e & 7;
            const float* base = qkv_b + n*QKV_ROW + h*HD + c*4;
            float4 fq = *(const float4*)(base);
            float4 fk = *(const float4*)(base + DIM);
            float4 fv = *(const float4*)(base + 2*DIM);
            ushort4 uq = { f2bf(fq.x), f2bf(fq.y), f2bf(fq.z), f2bf(fq.w) };
            ushort4 uk = { f2bf(fk.x), f2bf(fk.y), f2bf(fk.z), f2bf(fk.w) };
            *(ushort4*)&q_s[n*RSQ + c*4] = uq;
            *(ushort4*)&k_s[n*RSQ + c*4] = uk;
            int d0 = c*4;
            v_t[(d0+0)*RSV + n] = f2bf(fv.x);
            v_t[(d0+1)*RSV + n] = f2bf(fv.y);
            v_t[(d0+2)*RSV + n] = f2bf(fv.z);
            v_t[(d0+3)*RSV + n] = f2bf(fv.w);
        }
        __syncthreads();                           // B1: staged data visible

        // ---- PDSCA gates, no internal barriers (wave-internal LDS deps only) ----
        if (wv == 0) {
            // channel sums: 2 lanes per channel
            int c = ln & 31, p = ln >> 5;
            int s0 = p ? 25 : 0, s1 = p ? 49 : 25;
            float s = 0.f;
            int j = c*NN + s0;
            for (int sp = s0; sp < s1; ++sp, ++j)
                s += bf2f(xs[(j>>5)*RSQ + (j&31)]);
            s += __shfl_xor(s, 32);
            if (p == 0) sc[CM + c] = s * (1.f/NN);
            // MLP hidden: 8 lanes-per-output reduction
            int o = ln & 7, pp = ln >> 3;
            float4 w4 = *(const float4*)(ca_w1 + o*HD + pp*4);
            float4 m4 = *(const float4*)(sc + CM + pp*4);
            float a = w4.x*m4.x + w4.y*m4.y + w4.z*m4.z + w4.w*m4.w;
            a += __shfl_xor(a, 8);
            a += __shfl_xor(a, 16);
            a += __shfl_xor(a, 32);
            if (ln < 8) sc[HB + o] = gelu_tanh(a + ca_b1[o]);
            // channel out: 2 lanes per channel
            float4 w2 = *(const float4*)(ca_w2 + c*8 + p*4);
            float4 h4 = *(const float4*)(sc + HB + p*4);
            float a2 = w2.x*h4.x + w2.y*h4.y + w2.z*h4.z + w2.w*h4.w;
            a2 += __shfl_xor(a2, 32);
            if (p == 0) sc[CA + c] = a2 + ca_b2[c];
        } else if (ln < NN) {
            // spatial mean/max over channels
            int sp = ln;
            float sm = 0.f, mx = -1e30f;
            for (int c = 0; c < HD; ++c) {
                int j = c*NN + sp;
                float v = bf2f(xs[(j>>5)*RSQ + (j&31)]);
                sm += v; mx = fmaxf(mx, v);
            }
            sc[SM + sp] = sm * (1.f/HD);
            sc[SX + sp] = mx;
            // 7x7 SAME conv with clamped ranges (no per-tap branch)
            int y = sp / WS, x = sp - y*WS;
            int y0 = max(0, y-3), y1 = min(6, y+3);
            int x0 = max(0, x-3), x1 = min(6, x+3);
            float a = sab;
            for (int iy = y0; iy <= y1; ++iy) {
                int ky = iy - y + 3;
                for (int ix = x0; ix <= x1; ++ix) {
                    int kx = ix - x + 3;
                    int s2 = iy*WS + ix;
                    float wm = sc[SW + ky*WS + kx];
                    float wxv = sc[SW + NN + ky*WS + kx];
                    a += wm * sc[SM + s2] + wxv * sc[SX + s2];
                }
            }
            sc[SB + sp] = a;
        }
        __syncthreads();                           // B2: caout/sabuf cross-wave

        // sigmoid gate multiply (128 threads per half)
        for (int j2 = tt; j2 < NN*HD; j2 += 128) {
            int n = j2 >> 5, d = j2 & 31;
            int cc = j2 / NN, sp2 = j2 - cc*NN;
            int idx = n*RSQ + d;
            float v = bf2f(xs[idx]);
            float g = sc[CA + cc] + sc[SB + sp2];
            g = 1.f / (1.f + __expf(-g));
            xs[idx] = f2bf(v * g);
        }
        __syncthreads();                           // B3: gated q/k visible to all

        // ---- S = Q K^T ----
        bf16x8_t aq = *(const bf16x8_t*)&q_s[(w*16 + lrow)*RSQ + lk*8];
        f32x4_t sac[4];
        #pragma unroll
        for (int j = 0; j < 4; ++j) {
            bf16x8_t bk = *(const bf16x8_t*)&k_s[(j*16 + lrow)*RSQ + lk*8];
            f32x4_t z = (f32x4_t){0.f,0.f,0.f,0.f};
            sac[j] = MFMA16(aq, bk, z);
        }

        // ---- softmax (frag-layout bias: one float4 per row) ----
        const float* bias_f = bias_frag + h*64*64;
        #pragma unroll
        for (int r = 0; r < 4; ++r) {
            int row = w*16 + lk*4 + r;
            float4 b4 = *(const float4*)(bias_f + (row*16 + lrow)*4);
            float v0 = sac[0][r]*temp + b4.x;
            float v1 = sac[1][r]*temp + b4.y;
            float v2 = sac[2][r]*temp + b4.z;
            float v3 = (lrow == 0) ? (sac[3][r]*temp + b4.w) : -1e30f;
            float mx = fmaxf(fmaxf(v0, v1), fmaxf(v2, v3));
            mx = fmaxf(mx, __shfl_xor(mx, 1));
            mx = fmaxf(mx, __shfl_xor(mx, 2));
            mx = fmaxf(mx, __shfl_xor(mx, 4));
            mx = fmaxf(mx, __shfl_xor(mx, 8));
            float e0 = __expf(v0 - mx), e1 = __expf(v1 - mx);
            float e2 = __expf(v2 - mx), e3 = __expf(v3 - mx);
            float sum = e0 + e1 + e2 + e3;
            sum += __shfl_xor(sum, 1);
            sum += __shfl_xor(sum, 2);
            sum += __shfl_xor(sum, 4);
            sum += __shfl_xor(sum, 8);
            float inv = 1.f / sum;
            int pb = row*RSV + lrow;
            p_s[pb +  0] = f2bf(e0 * inv);
            p_s[pb + 16] = f2bf(e1 * inv);
            p_s[pb + 32] = f2bf(e2 * inv);
            p_s[pb + 48] = f2bf(e3 * inv);
        }
        // no barrier: P strip + O strip are same-wave (lgkmcnt ordering)

        // ---- O = P V ----
        f32x4_t oac[2];
        oac[0] = (f32x4_t){0.f,0.f,0.f,0.f};
        oac[1] = (f32x4_t){0.f,0.f,0.f,0.f};
        #pragma unroll
        for (int ks = 0; ks < 2; ++ks) {
            bf16x8_t ap = *(const bf16x8_t*)&p_s[(w*16 + lrow)*RSV + ks*32 + lk*8];
            #pragma unroll
            for (int nt = 0; nt < 2; ++nt) {
                bf16x8_t bv = *(const bf16x8_t*)&v_t[(nt*16 + lrow)*RSV + ks*32 + lk*8];
                oac[nt] = MFMA16(ap, bv, oac[nt]);
            }
        }
        #pragma unroll
        for (int nt = 0; nt < 2; ++nt)
            #pragma unroll
            for (int r = 0; r < 4; ++r)
                q_s[(w*16 + lk*4 + r)*RSQ + nt*16 + lrow] = f2bf(oac[nt][r]);

        // ---- projection partials, W B-frags streamed from L2 (bf16, const) ----
        bf16x8_t ao = *(const bf16x8_t*)&q_s[(w*16 + lrow)*RSQ + lk*8];
        #pragma unroll
        for (int j = 0; j < 12; ++j) {
            bf16x8_t bwf = *(const bf16x8_t*)(wbf + (j*16 + lrow)*DIM + h*HD + lk*8);
            pacc[j] = MFMA16(ao, bwf, pacc[j]);
        }
        __syncthreads();                           // B4: end of head
    }

    float* out_b = out + (size_t)b * (NN*DIM);
    #pragma unroll
    for (int j = 0; j < 12; ++j) {
        #pragma unroll
        for (int r = 0; r < 4; ++r) {
            int row = w*16 + lk*4 + r;
            if (row < NN)
                out_b[row*DIM + j*16 + lrow] = pacc[j][r];
        }
    }
}

extern "C" void kernel_launch(void* const* d_in, const int* in_sizes, int n_in,
                              void* d_out, int out_size, void* d_ws, size_t ws_size,
                              hipStream_t stream)
{
    (void)in_sizes; (void)n_in; (void)out_size; (void)ws_size;
    const float* qkv      = (const float*)d_in[0];
    const float* log_temp = (const float*)d_in[1];
    const float* pos_w    = (const float*)d_in[2];
    /* d_in[3] = pos_b cancels in pairwise diff */
    const float* pos_scale= (const float*)d_in[4];
    const float* meta_w1  = (const float*)d_in[5];
    const float* meta_b1  = (const float*)d_in[6];
    const float* meta_w2  = (const float*)d_in[7];
    const float* meta_b2  = (const float*)d_in[8];
    const float* q_ca_w1  = (const float*)d_in[9];
    const float* q_ca_b1  = (const float*)d_in[10];
    const float* q_ca_w2  = (const float*)d_in[11];
    const float* q_ca_b2  = (const float*)d_in[12];
    const float* q_sa_w   = (const float*)d_in[13];
    const float* q_sa_b   = (const float*)d_in[14];
    const float* k_ca_w1  = (const float*)d_in[15];
    const float* k_ca_b1  = (const float*)d_in[16];
    const float* k_ca_w2  = (const float*)d_in[17];
    const float* k_ca_b2  = (const float*)d_in[18];
    const float* k_sa_w   = (const float*)d_in[19];
    const float* k_sa_b   = (const float*)d_in[20];
    const float* proj_w   = (const float*)d_in[21];
    float* out = (float*)d_out;

    float* bias_frag = (float*)d_ws;
    unsigned short* wbf = (unsigned short*)((char*)d_ws + WBF_OFF_B);

    hipLaunchKernelGGL(bias_kernel, dim3(NN*NN), dim3(128), 0, stream,
                       pos_w, pos_scale, meta_w1, meta_b1, meta_w2, meta_b2, bias_frag);
    hipLaunchKernelGGL(prep_w, dim3((DIM*DIM + HEADS*15*64 + 255)/256), dim3(256), 0, stream,
                       proj_w, wbf, bias_frag);
    hipLaunchKernelGGL(win_attn_mfma, dim3(NWIN), dim3(256), 0, stream,
                       qkv, log_temp,
                       q_ca_w1, q_ca_b1, q_ca_w2, q_ca_b2, q_sa_w, q_sa_b,
                       k_ca_w1, k_ca_b1, k_ca_w2, k_ca_b2, k_sa_w, k_sa_b,
                       bias_frag, wbf, out);
}

// Round 4
// 470.554 us; speedup vs baseline: 1.5521x; 1.5521x over previous
//
#include <hip/hip_runtime.h>
#include <math.h>

#define DIM 192
#define HEADS 6
#define HD 32
#define WS 7
#define NN 49
#define NWIN 4096
#define QKV_ROW (3*DIM)

typedef __attribute__((ext_vector_type(8))) short bf16x8_t;
typedef __attribute__((ext_vector_type(4))) float f32x4_t;

#define MFMA16(a,b,c) __builtin_amdgcn_mfma_f32_16x16x32_bf16((a),(b),(c),0,0,0)

__device__ __forceinline__ float gelu_tanh(float x) {
    const float k0 = 0.7978845608028654f; // sqrt(2/pi)
    const float k1 = 0.044715f;
    float t = tanhf(k0 * (x + k1 * x * x * x));
    return 0.5f * x * (1.0f + t);
}

// native bf16 casts -> compiler emits packed v_cvt_pk_bf16_f32 (RNE)
__device__ __forceinline__ unsigned short f2bf(float f) {
    __bf16 h = (__bf16)f;
    return __builtin_bit_cast(unsigned short, h);
}
__device__ __forceinline__ float bf2f(unsigned short u) {
    return (float)__builtin_bit_cast(__bf16, u);
}

// ws layout: bias_frag (6*64*64 f32 = 98304 B) | wbf (192*192 bf16 = 73728 B)
#define BIASF_FLOATS (HEADS*64*64)
#define WBF_OFF_B    (BIASF_FLOATS*4)

// ---------------- bias kernel: frag layout [h][row64][lrow16][4] ----------------
__global__ __launch_bounds__(128) void bias_kernel(
    const float* __restrict__ pos_w, const float* __restrict__ pos_scale,
    const float* __restrict__ meta_w1, const float* __restrict__ meta_b1,
    const float* __restrict__ meta_w2, const float* __restrict__ meta_b2,
    float* __restrict__ bias_frag)
{
    const int p = blockIdx.x;          // n*49+m
    const int n = p / NN, m = p % NN;
    const int i = threadIdx.x;         // 0..127
    __shared__ float hbuf[128];
    const float step = 2.0f / 6.0f;
    const float dx = (float)((n % WS) - (m % WS)) * step;
    const float dy = (float)((n / WS) - (m / WS)) * step;
    const float ps = pos_scale[0];
    float a = meta_b1[i];
    for (int d = 0; d < DIM; ++d) {
        float rel = ps * (pos_w[2*d] * dx + pos_w[2*d+1] * dy); // pos_b cancels
        a += rel * meta_w1[d*128 + i];
    }
    hbuf[i] = gelu_tanh(a);
    __syncthreads();
    if (i < HEADS) {
        float b = meta_b2[i];
        for (int j = 0; j < 128; ++j) b += hbuf[j] * meta_w2[j*HEADS + i];
        bias_frag[((i*64 + n)*16 + (m & 15))*4 + (m >> 4)] = b;
    }
}

// ---------------- prep: W -> bf16, zero bias_frag pad rows ----------------
__global__ __launch_bounds__(256) void prep_w(
    const float* __restrict__ proj_w, unsigned short* __restrict__ wbf,
    float* __restrict__ bias_frag)
{
    int idx = blockIdx.x*256 + threadIdx.x;
    if (idx < DIM*DIM) wbf[idx] = f2bf(proj_w[idx]);
    int z = idx - DIM*DIM;
    if (z >= 0 && z < HEADS*15*64) {
        int hh = z / 960, rem = z - hh*960;
        int row = 49 + (rem >> 6), inner = rem & 63;
        bias_frag[(hh*64 + row)*64 + inner] = 0.f;
    }
}

// gate scratch layout (floats, per half; half stride 320 for 16B alignment)
#define CM 0
#define HB 32
#define CA 40
#define SM 72
#define SX 121
#define SB 170
#define SW 219   // sa_w copy, 98 floats
#define GSZ 320

// LDS row strides (bf16 elems)
#define RSQ 40   // q_s/k_s: 80B
#define RSV 72   // v_t/p_s: 144B

__global__ __launch_bounds__(256, 3) void win_attn_mfma(
    const float* __restrict__ qkv,
    const float* __restrict__ log_temp,
    const float* __restrict__ q_ca_w1, const float* __restrict__ q_ca_b1,
    const float* __restrict__ q_ca_w2, const float* __restrict__ q_ca_b2,
    const float* __restrict__ q_sa_w, const float* __restrict__ q_sa_b,
    const float* __restrict__ k_ca_w1, const float* __restrict__ k_ca_b1,
    const float* __restrict__ k_ca_w2, const float* __restrict__ k_ca_b2,
    const float* __restrict__ k_sa_w, const float* __restrict__ k_sa_b,
    const float* __restrict__ bias_frag,
    const unsigned short* __restrict__ wbf,
    float* __restrict__ out)
{
    __shared__ unsigned short q_s[64*RSQ];   // gated Q, later O
    __shared__ unsigned short k_s[64*RSQ];   // gated K
    __shared__ unsigned short v_t[32*RSV];   // V^T [d][m]
    __shared__ unsigned short p_s[64*RSV];   // P [n][m]
    __shared__ float gsc[2*GSZ];

    const int t = threadIdx.x;
    const int b = blockIdx.x;
    const int l = t & 63;
    const int w = t >> 6;          // wave / row-strip
    const int lrow = l & 15;
    const int lk = l >> 4;
    const float temp = __expf(log_temp[0]);
    const float* qkv_b = qkv + (size_t)b * (NN*QKV_ROW);

    // gate partition: threads 0-127 -> q; 128-255 -> k
    const int kh = t >> 7;
    const int tt = t & 127;
    const int wv = tt >> 6;        // gate-wave within half
    const int ln = tt & 63;
    unsigned short* xs = kh ? k_s : q_s;
    const float* ca_w1 = kh ? k_ca_w1 : q_ca_w1;
    const float* ca_b1 = kh ? k_ca_b1 : q_ca_b1;
    const float* ca_w2 = kh ? k_ca_w2 : q_ca_w2;
    const float* ca_b2 = kh ? k_ca_b2 : q_ca_b2;
    const float* sa_w  = kh ? k_sa_w  : q_sa_w;
    const float* sa_b  = kh ? k_sa_b  : q_sa_b;
    float* sc = gsc + kh*GSZ;
    const float sab = sa_b[0];

    f32x4_t pacc[12];
    #pragma unroll
    for (int j = 0; j < 12; ++j) pacc[j] = (f32x4_t){0.f,0.f,0.f,0.f};

    // one-time: zero pads, cache sa_w in LDS
    for (int i = t; i < 15*RSQ; i += 256) { q_s[49*RSQ + i] = 0; k_s[49*RSQ + i] = 0; }
    for (int i = t; i < 32*23; i += 256) { int d = i/23, m = 49 + (i - d*23); v_t[d*RSV + m] = 0; }
    if (tt < 2*NN) sc[SW + tt] = sa_w[tt];

    #pragma unroll 1
    for (int h = 0; h < HEADS; ++h) {
        // ---- stage q,k,v head slice (fp32 -> bf16) ----
        for (int e = t; e < NN*8; e += 256) {
            int n = e >> 3, c = e & 7;
            const float* base = qkv_b + n*QKV_ROW + h*HD + c*4;
            float4 fq = *(const float4*)(base);
            float4 fk = *(const float4*)(base + DIM);
            float4 fv = *(const float4*)(base + 2*DIM);
            ushort4 uq = { f2bf(fq.x), f2bf(fq.y), f2bf(fq.z), f2bf(fq.w) };
            ushort4 uk = { f2bf(fk.x), f2bf(fk.y), f2bf(fk.z), f2bf(fk.w) };
            *(ushort4*)&q_s[n*RSQ + c*4] = uq;
            *(ushort4*)&k_s[n*RSQ + c*4] = uk;
            int d0 = c*4;
            v_t[(d0+0)*RSV + n] = f2bf(fv.x);
            v_t[(d0+1)*RSV + n] = f2bf(fv.y);
            v_t[(d0+2)*RSV + n] = f2bf(fv.z);
            v_t[(d0+3)*RSV + n] = f2bf(fv.w);
        }
        __syncthreads();                           // B1: staged data visible

        // ---- PDSCA gates, no internal barriers (wave-internal LDS deps only) ----
        if (wv == 0) {
            // channel sums: 2 lanes per channel
            int c = ln & 31, p = ln >> 5;
            int s0 = p ? 25 : 0, s1 = p ? 49 : 25;
            float s = 0.f;
            int j = c*NN + s0;
            for (int sp = s0; sp < s1; ++sp, ++j)
                s += bf2f(xs[(j>>5)*RSQ + (j&31)]);
            s += __shfl_xor(s, 32);
            if (p == 0) sc[CM + c] = s * (1.f/NN);
            // MLP hidden: 8 lanes-per-output reduction
            int o = ln & 7, pp = ln >> 3;
            float4 w4 = *(const float4*)(ca_w1 + o*HD + pp*4);
            float4 m4 = *(const float4*)(sc + CM + pp*4);
            float a = w4.x*m4.x + w4.y*m4.y + w4.z*m4.z + w4.w*m4.w;
            a += __shfl_xor(a, 8);
            a += __shfl_xor(a, 16);
            a += __shfl_xor(a, 32);
            if (ln < 8) sc[HB + o] = gelu_tanh(a + ca_b1[o]);
            // channel out: 2 lanes per channel
            float4 w2 = *(const float4*)(ca_w2 + c*8 + p*4);
            float4 h4 = *(const float4*)(sc + HB + p*4);
            float a2 = w2.x*h4.x + w2.y*h4.y + w2.z*h4.z + w2.w*h4.w;
            a2 += __shfl_xor(a2, 32);
            if (p == 0) sc[CA + c] = a2 + ca_b2[c];
        } else if (ln < NN) {
            // spatial mean/max over channels
            int sp = ln;
            float sm = 0.f, mx = -1e30f;
            for (int c = 0; c < HD; ++c) {
                int j = c*NN + sp;
                float v = bf2f(xs[(j>>5)*RSQ + (j&31)]);
                sm += v; mx = fmaxf(mx, v);
            }
            sc[SM + sp] = sm * (1.f/HD);
            sc[SX + sp] = mx;
            // 7x7 SAME conv with clamped ranges (no per-tap branch)
            int y = sp / WS, x = sp - y*WS;
            int y0 = max(0, y-3), y1 = min(6, y+3);
            int x0 = max(0, x-3), x1 = min(6, x+3);
            float a = sab;
            for (int iy = y0; iy <= y1; ++iy) {
                int ky = iy - y + 3;
                for (int ix = x0; ix <= x1; ++ix) {
                    int kx = ix - x + 3;
                    int s2 = iy*WS + ix;
                    float wm = sc[SW + ky*WS + kx];
                    float wxv = sc[SW + NN + ky*WS + kx];
                    a += wm * sc[SM + s2] + wxv * sc[SX + s2];
                }
            }
            sc[SB + sp] = a;
        }
        __syncthreads();                           // B2: caout/sabuf cross-wave

        // sigmoid gate multiply (128 threads per half)
        for (int j2 = tt; j2 < NN*HD; j2 += 128) {
            int n = j2 >> 5, d = j2 & 31;
            int cc = j2 / NN, sp2 = j2 - cc*NN;
            int idx = n*RSQ + d;
            float v = bf2f(xs[idx]);
            float g = sc[CA + cc] + sc[SB + sp2];
            g = 1.f / (1.f + __expf(-g));
            xs[idx] = f2bf(v * g);
        }
        __syncthreads();                           // B3: gated q/k visible to all

        // ---- S = Q K^T ----
        bf16x8_t aq = *(const bf16x8_t*)&q_s[(w*16 + lrow)*RSQ + lk*8];
        f32x4_t sac[4];
        #pragma unroll
        for (int j = 0; j < 4; ++j) {
            bf16x8_t bk = *(const bf16x8_t*)&k_s[(j*16 + lrow)*RSQ + lk*8];
            f32x4_t z = (f32x4_t){0.f,0.f,0.f,0.f};
            sac[j] = MFMA16(aq, bk, z);
        }

        // ---- softmax (frag-layout bias: one float4 per row) ----
        const float* bias_f = bias_frag + h*64*64;
        #pragma unroll
        for (int r = 0; r < 4; ++r) {
            int row = w*16 + lk*4 + r;
            float4 b4 = *(const float4*)(bias_f + (row*16 + lrow)*4);
            float v0 = sac[0][r]*temp + b4.x;
            float v1 = sac[1][r]*temp + b4.y;
            float v2 = sac[2][r]*temp + b4.z;
            float v3 = (lrow == 0) ? (sac[3][r]*temp + b4.w) : -1e30f;
            float mx = fmaxf(fmaxf(v0, v1), fmaxf(v2, v3));
            mx = fmaxf(mx, __shfl_xor(mx, 1));
            mx = fmaxf(mx, __shfl_xor(mx, 2));
            mx = fmaxf(mx, __shfl_xor(mx, 4));
            mx = fmaxf(mx, __shfl_xor(mx, 8));
            float e0 = __expf(v0 - mx), e1 = __expf(v1 - mx);
            float e2 = __expf(v2 - mx), e3 = __expf(v3 - mx);
            float sum = e0 + e1 + e2 + e3;
            sum += __shfl_xor(sum, 1);
            sum += __shfl_xor(sum, 2);
            sum += __shfl_xor(sum, 4);
            sum += __shfl_xor(sum, 8);
            float inv = 1.f / sum;
            int pb = row*RSV + lrow;
            p_s[pb +  0] = f2bf(e0 * inv);
            p_s[pb + 16] = f2bf(e1 * inv);
            p_s[pb + 32] = f2bf(e2 * inv);
            p_s[pb + 48] = f2bf(e3 * inv);
        }
        // no barrier: P strip + O strip are same-wave (lgkmcnt ordering)

        // ---- O = P V ----
        f32x4_t oac[2];
        oac[0] = (f32x4_t){0.f,0.f,0.f,0.f};
        oac[1] = (f32x4_t){0.f,0.f,0.f,0.f};
        #pragma unroll
        for (int ks = 0; ks < 2; ++ks) {
            bf16x8_t ap = *(const bf16x8_t*)&p_s[(w*16 + lrow)*RSV + ks*32 + lk*8];
            #pragma unroll
            for (int nt = 0; nt < 2; ++nt) {
                bf16x8_t bv = *(const bf16x8_t*)&v_t[(nt*16 + lrow)*RSV + ks*32 + lk*8];
                oac[nt] = MFMA16(ap, bv, oac[nt]);
            }
        }
        #pragma unroll
        for (int nt = 0; nt < 2; ++nt)
            #pragma unroll
            for (int r = 0; r < 4; ++r)
                q_s[(w*16 + lk*4 + r)*RSQ + nt*16 + lrow] = f2bf(oac[nt][r]);

        // ---- projection partials, W B-frags streamed from L2 (bf16, const) ----
        bf16x8_t ao = *(const bf16x8_t*)&q_s[(w*16 + lrow)*RSQ + lk*8];
        #pragma unroll
        for (int j = 0; j < 12; ++j) {
            bf16x8_t bwf = *(const bf16x8_t*)(wbf + (j*16 + lrow)*DIM + h*HD + lk*8);
            pacc[j] = MFMA16(ao, bwf, pacc[j]);
        }
        __syncthreads();                           // B4: end of head
    }

    float* out_b = out + (size_t)b * (NN*DIM);
    #pragma unroll
    for (int j = 0; j < 12; ++j) {
        #pragma unroll
        for (int r = 0; r < 4; ++r) {
            int row = w*16 + lk*4 + r;
            if (row < NN)
                out_b[row*DIM + j*16 + lrow] = pacc[j][r];
        }
    }
}

extern "C" void kernel_launch(void* const* d_in, const int* in_sizes, int n_in,
                              void* d_out, int out_size, void* d_ws, size_t ws_size,
                              hipStream_t stream)
{
    (void)in_sizes; (void)n_in; (void)out_size; (void)ws_size;
    const float* qkv      = (const float*)d_in[0];
    const float* log_temp = (const float*)d_in[1];
    const float* pos_w    = (const float*)d_in[2];
    /* d_in[3] = pos_b cancels in pairwise diff */
    const float* pos_scale= (const float*)d_in[4];
    const float* meta_w1  = (const float*)d_in[5];
    const float* meta_b1  = (const float*)d_in[6];
    const float* meta_w2  = (const float*)d_in[7];
    const float* meta_b2  = (const float*)d_in[8];
    const float* q_ca_w1  = (const float*)d_in[9];
    const float* q_ca_b1  = (const float*)d_in[10];
    const float* q_ca_w2  = (const float*)d_in[11];
    const float* q_ca_b2  = (const float*)d_in[12];
    const float* q_sa_w   = (const float*)d_in[13];
    const float* q_sa_b   = (const float*)d_in[14];
    const float* k_ca_w1  = (const float*)d_in[15];
    const float* k_ca_b1  = (const float*)d_in[16];
    const float* k_ca_w2  = (const float*)d_in[17];
    const float* k_ca_b2  = (const float*)d_in[18];
    const float* k_sa_w   = (const float*)d_in[19];
    const float* k_sa_b   = (const float*)d_in[20];
    const float* proj_w   = (const float*)d_in[21];
    float* out = (float*)d_out;

    float* bias_frag = (float*)d_ws;
    unsigned short* wbf = (unsigned short*)((char*)d_ws + WBF_OFF_B);

    hipLaunchKernelGGL(bias_kernel, dim3(NN*NN), dim3(128), 0, stream,
                       pos_w, pos_scale, meta_w1, meta_b1, meta_w2, meta_b2, bias_frag);
    hipLaunchKernelGGL(prep_w, dim3((DIM*DIM + HEADS*15*64 + 255)/256), dim3(256), 0, stream,
                       proj_w, wbf, bias_frag);
    hipLaunchKernelGGL(win_attn_mfma, dim3(NWIN), dim3(256), 0, stream,
                       qkv, log_temp,
                       q_ca_w1, q_ca_b1, q_ca_w2, q_ca_b2, q_sa_w, q_sa_b,
                       k_ca_w1, k_ca_b1, k_ca_w2, k_ca_b2, k_sa_w, k_sa_b,
                       bias_frag, wbf, out);
}